// Round 1
// baseline (354.289 us; speedup 1.0000x reference)
//
#include <hip/hip_runtime.h>

// HamiltonianMetric: y[b] = u^T u, u = scatter(tanh(MLP(x))), fused bf16-MFMA kernel.
// B=32768, D=64, H=256, T=2080. Output 512MB f32 (HBM-write floor ~83us).

typedef __bf16 bf16_t;
typedef bf16_t bf16x8 __attribute__((ext_vector_type(8)));
typedef float  f32x4  __attribute__((ext_vector_type(4)));

#define MFMA16(a, b, c) __builtin_amdgcn_mfma_f32_16x16x32_bf16((a), (b), (c), 0, 0, 0)

__device__ __forceinline__ float fast_tanh(float x) {
  float cx = fminf(fmaxf(x, -30.0f), 30.0f);
  float t  = __expf(2.0f * cx);
  return (t - 1.0f) * __builtin_amdgcn_rcpf(t + 1.0f);
}

// Zero frag elements with k = kbase+e > row (strict-lower garbage in uT slots).
__device__ __forceinline__ bf16x8 mask_frag(bf16x8 f, int row, int kbase) {
  int eb = row - kbase;  // keep element e iff e <= eb
  union { bf16x8 v; unsigned int u[4]; } xx;
  xx.v = f;
#pragma unroll
  for (int p = 0; p < 4; ++p) {
    unsigned int word = xx.u[p];
    word = (eb >= 2 * p + 1) ? word : ((eb >= 2 * p) ? (word & 0xFFFFu) : 0u);
    xx.u[p] = word;
  }
  return xx.v;
}

// ---- prep: W1[64][256]->W1t bf16[256][64]; W2[256][256]->W2t[256][256];
//            W3[256][2080]->W3t[2080][256]  (all K-contiguous per output row)
__global__ void prep_kernel(const float* __restrict__ W1, const float* __restrict__ W2,
                            const float* __restrict__ W3, bf16_t* __restrict__ ws) {
  int tid = blockIdx.x * 512 + threadIdx.x;  // 614400 total
  if (tid < 16384) {
    int n = tid >> 6, k = tid & 63;
    ws[tid] = (bf16_t)W1[k * 256 + n];
  } else if (tid < 81920) {
    int m = tid - 16384;
    int n = m >> 8, k = m & 255;
    ws[tid] = (bf16_t)W2[k * 256 + n];
  } else {
    int m = tid - 81920;
    int n = m >> 8, k = m & 255;
    ws[tid] = (bf16_t)W3[k * 2080 + n];
  }
}

__global__ void __launch_bounds__(512, 2)
hm_kernel(const float* __restrict__ x, const float* __restrict__ b1,
          const float* __restrict__ b2, const float* __restrict__ b3,
          const bf16_t* __restrict__ ws, float* __restrict__ out) {
  extern __shared__ char smem[];  // 131072 B arena
  const int tid  = threadIdx.x;
  const int w    = tid >> 6;   // wave 0..7
  const int lane = tid & 63;
  const int g    = lane >> 4;  // 0..3
  const int c    = lane & 15;  // 0..15
  const int blk  = blockIdx.x;

  const bf16_t* W1t = ws;           // [256][64]
  const bf16_t* W2t = ws + 16384;   // [256][256]
  const bf16_t* W3t = ws + 81920;   // [2080][256]

  char* h2s = smem;           // [64][256] bf16 (32KB), row-XOR-swizzled
  char* xs  = smem + 32768;   // [64][64]  bf16 (8KB)
  char* h1s = smem + 40960;   // [64][256] bf16 (32KB)

  // ---------------- load x tile (64 rows f32 -> bf16 LDS) ----------------
#pragma unroll
  for (int i = 0; i < 2; ++i) {
    int idx = i * 2048 + tid * 4;
    f32x4 v = *(const f32x4*)(x + (size_t)blk * 4096 + idx);
    int row = idx >> 6, col = idx & 63;
    union { bf16_t b[4]; unsigned long long u64; } p;
    p.b[0] = (bf16_t)v[0]; p.b[1] = (bf16_t)v[1];
    p.b[2] = (bf16_t)v[2]; p.b[3] = (bf16_t)v[3];
    *(unsigned long long*)(xs + ((row * 128 + col * 2) ^ ((row & 7) << 4))) = p.u64;
  }
  __syncthreads();

  // ---------------- stage 1: h1 = tanh(x @ W1 + b1) ----------------
  {
    bf16x8 a1[4][2];
#pragma unroll
    for (int mt = 0; mt < 4; ++mt)
#pragma unroll
      for (int kk = 0; kk < 2; ++kk) {
        int row = mt * 16 + c;
        a1[mt][kk] = *(const bf16x8*)(xs + ((row * 128 + kk * 64 + g * 16) ^ ((row & 7) << 4)));
      }
#pragma unroll
    for (int ni = 0; ni < 2; ++ni) {
      int nt = w + ni * 8;
      int n  = nt * 16 + c;
      bf16x8 bw0 = *(const bf16x8*)(W1t + n * 64 + g * 8);
      bf16x8 bw1 = *(const bf16x8*)(W1t + n * 64 + 32 + g * 8);
      float bias = b1[n];
#pragma unroll
      for (int mt = 0; mt < 4; ++mt) {
        f32x4 acc = {0.f, 0.f, 0.f, 0.f};
        acc = MFMA16(a1[mt][0], bw0, acc);
        acc = MFMA16(a1[mt][1], bw1, acc);
#pragma unroll
        for (int r = 0; r < 4; ++r) {
          int row = mt * 16 + g * 4 + r;
          float v = fast_tanh(acc[r] + bias);
          *(bf16_t*)(h1s + ((row * 512 + n * 2) ^ ((row & 7) << 4))) = (bf16_t)v;
        }
      }
    }
  }
  __syncthreads();

  // ---------------- stage 2: h2 = tanh(h1 @ W2 + b2) ----------------
#pragma unroll
  for (int ni = 0; ni < 2; ++ni) {
    int nt = w + ni * 8;
    int n  = nt * 16 + c;
    bf16x8 bw[8];
#pragma unroll
    for (int kk = 0; kk < 8; ++kk)
      bw[kk] = *(const bf16x8*)(W2t + n * 256 + kk * 32 + g * 8);
    float bias = b2[n];
#pragma unroll
    for (int mt = 0; mt < 4; ++mt) {
      int row = mt * 16 + c;
      f32x4 acc0 = {0.f, 0.f, 0.f, 0.f}, acc1 = {0.f, 0.f, 0.f, 0.f};
#pragma unroll
      for (int kk = 0; kk < 8; kk += 2) {
        bf16x8 a0 = *(const bf16x8*)(h1s + ((row * 512 + kk * 64 + g * 16) ^ ((row & 7) << 4)));
        bf16x8 a1 = *(const bf16x8*)(h1s + ((row * 512 + (kk + 1) * 64 + g * 16) ^ ((row & 7) << 4)));
        acc0 = MFMA16(a0, bw[kk], acc0);
        acc1 = MFMA16(a1, bw[kk + 1], acc1);
      }
      f32x4 acc = acc0 + acc1;
#pragma unroll
      for (int r = 0; r < 4; ++r) {
        int orow = mt * 16 + g * 4 + r;
        float v = fast_tanh(acc[r] + bias);
        *(bf16_t*)(h2s + ((orow * 512 + n * 2) ^ ((orow & 7) << 4))) = (bf16_t)v;
      }
    }
  }
  __syncthreads();

  // Hoist ALL stage-3 A-fragments (h2) into registers, then free the arena.
  bf16x8 h2f[4][8];
#pragma unroll
  for (int sg = 0; sg < 4; ++sg)
#pragma unroll
    for (int kk = 0; kk < 8; ++kk) {
      int row = sg * 16 + c;
      h2f[sg][kk] = *(const bf16x8*)(h2s + ((row * 512 + kk * 64 + g * 16) ^ ((row & 7) << 4)));
    }
  __syncthreads();  // arena now free: 16 uT slots of 8KB each

  // ---------------- stages 3+4 per sub-group of 16 batches ----------------
#pragma unroll
  for (int sg = 0; sg < 4; ++sg) {
    // stage 3: t-tiles -> tanh -> scatter bf16 into uT[j][k] (swizzled). No
    // zero-fill: k>j garbage is masked in stage 4.
    for (int nt = w; nt < 130; nt += 8) {
      int n = nt * 16 + c;
      bf16x8 bw[8];
#pragma unroll
      for (int kk = 0; kk < 8; ++kk)
        bw[kk] = *(const bf16x8*)(W3t + n * 256 + kk * 32 + g * 8);
      f32x4 acc0 = {0.f, 0.f, 0.f, 0.f}, acc1 = {0.f, 0.f, 0.f, 0.f};
#pragma unroll
      for (int kk = 0; kk < 8; kk += 2) {
        acc0 = MFMA16(h2f[sg][kk], bw[kk], acc0);
        acc1 = MFMA16(h2f[sg][kk + 1], bw[kk + 1], acc1);
      }
      f32x4 acc = acc0 + acc1;
      float bias = b3[n];
      // decode t-index n -> (k=kd, j=jd) of u (uT row jd, col kd); same for all r.
      int kd, jd;
      if (n < 64) {
        kd = n; jd = n;
      } else {
        int e = n - 64;
        int i0 = (int)((127.0f - sqrtf(16129.0f - 8.0f * (float)e)) * 0.5f);
        i0 = i0 < 0 ? 0 : (i0 > 62 ? 62 : i0);
        if ((((i0 + 1) * (126 - i0)) >> 1) <= e) ++i0;
        else if (((i0 * (127 - i0)) >> 1) > e) --i0;
        kd = i0;
        jd = e - ((i0 * (127 - i0)) >> 1) + i0 + 1;
      }
      int uoff = (jd * 128 + kd * 2) ^ ((jd & 7) << 4);
#pragma unroll
      for (int r = 0; r < 4; ++r) {
        int m = g * 4 + r;  // batch within sub-group
        float v = fast_tanh(acc[r] + bias);
        *(bf16_t*)(smem + m * 8192 + uoff) = (bf16_t)v;
      }
    }
    __syncthreads();

    // stage 4: each wave computes y = Gram(uT rows) for 2 batches.
#pragma unroll
    for (int bi = 0; bi < 2; ++bi) {
      char* slot = smem + (w * 2 + bi) * 8192;
      // frag(ti,kk): rows ti*16+c, k-slice kk*32+g*8.. ; (0,1),(1,1) are all-zero -> skipped
      bf16x8 f0  = *(const bf16x8*)(slot + (((0  + c) * 128 + g * 16)       ^ (((0  + c) & 7) << 4)));
      bf16x8 f1  = *(const bf16x8*)(slot + (((16 + c) * 128 + g * 16)       ^ (((16 + c) & 7) << 4)));
      bf16x8 f2  = *(const bf16x8*)(slot + (((32 + c) * 128 + g * 16)       ^ (((32 + c) & 7) << 4)));
      bf16x8 f3  = *(const bf16x8*)(slot + (((48 + c) * 128 + g * 16)       ^ (((48 + c) & 7) << 4)));
      bf16x8 f2b = *(const bf16x8*)(slot + (((32 + c) * 128 + 64 + g * 16)  ^ (((32 + c) & 7) << 4)));
      bf16x8 f3b = *(const bf16x8*)(slot + (((48 + c) * 128 + 64 + g * 16)  ^ (((48 + c) & 7) << 4)));
      f0  = mask_frag(f0, c, g * 8);
      f1  = mask_frag(f1, 16 + c, g * 8);
      f2b = mask_frag(f2b, 32 + c, 32 + g * 8);
      f3b = mask_frag(f3b, 48 + c, 32 + g * 8);

      bf16x8 fA[4] = {f0, f1, f2, f3};
      f32x4 acc[4][4];
#pragma unroll
      for (int ti = 0; ti < 4; ++ti)
#pragma unroll
        for (int tj = 0; tj < 4; ++tj) {
          f32x4 a = {0.f, 0.f, 0.f, 0.f};
          acc[ti][tj] = MFMA16(fA[ti], fA[tj], a);
        }
      acc[2][2] = MFMA16(f2b, f2b, acc[2][2]);
      acc[2][3] = MFMA16(f2b, f3b, acc[2][3]);
      acc[3][2] = MFMA16(f3b, f2b, acc[3][2]);
      acc[3][3] = MFMA16(f3b, f3b, acc[3][3]);

      // write y via LDS staging (slot is dead now) for full-line stores
      int batch  = blk * 64 + sg * 16 + w * 2 + bi;
      float* yb  = out + (size_t)batch * 4096;
#pragma unroll
      for (int hh = 0; hh < 2; ++hh) {
#pragma unroll
        for (int t2 = 0; t2 < 2; ++t2) {
          int ti = hh * 2 + t2;
#pragma unroll
          for (int tj = 0; tj < 4; ++tj)
#pragma unroll
            for (int r = 0; r < 4; ++r) {
              int rloc = t2 * 16 + g * 4 + r;
              *(float*)(slot + rloc * 256 + (tj * 16 + c) * 4) = acc[ti][tj][r];
            }
        }
#pragma unroll
        for (int ii = 0; ii < 8; ++ii) {
          f32x4 v = *(const f32x4*)(slot + ii * 1024 + lane * 16);
          *(f32x4*)(yb + hh * 2048 + ii * 256 + lane * 4) = v;
        }
      }
    }
    __syncthreads();
  }
}

extern "C" void kernel_launch(void* const* d_in, const int* in_sizes, int n_in,
                              void* d_out, int out_size, void* d_ws, size_t ws_size,
                              hipStream_t stream) {
  (void)in_sizes; (void)n_in; (void)out_size; (void)ws_size;
  const float* x  = (const float*)d_in[0];
  const float* W1 = (const float*)d_in[1];
  const float* b1 = (const float*)d_in[2];
  const float* W2 = (const float*)d_in[3];
  const float* b2 = (const float*)d_in[4];
  const float* W3 = (const float*)d_in[5];
  const float* b3 = (const float*)d_in[6];
  bf16_t* ws = (bf16_t*)d_ws;   // needs 1,228,800 B
  float* out = (float*)d_out;

  prep_kernel<<<1200, 512, 0, stream>>>(W1, W2, W3, ws);

  hipFuncSetAttribute((const void*)hm_kernel,
                      hipFuncAttributeMaxDynamicSharedMemorySize, 131072);
  hm_kernel<<<512, 512, 131072, stream>>>(x, b1, b2, b3, ws, out);
}